// Round 3
// baseline (1185.859 us; speedup 1.0000x reference)
//
#include <hip/hip_runtime.h>
#include <hip/hip_bf16.h>

// GraphLSTM: B=128, S=128, N=24, F=16, H=32 -> IS=384, HS=768, gates=3072.
// R10: epoch-tagged h exchange. Each producer stores one relaxed agent-scope
// u64 {tag = t+1 (hi32), packed bf16 pair (lo32)} per (batch, j-pair).
// Consumers poll the DATA: issue all 24 u64 loads, overlap x-staging under
// them, retry stale entries until every tag == t+1. This removes the entire
// control chain of the 640us baseline (producer vmcnt drain -> tid0 counter
// RMW -> s_sleep poll -> separate data loads): exchange cost drops from
// ~3-4 serial agent round-trips to ~1-1.5. Liveness is unconditional
// (producers store before they can block; tags monotone per ping-pong
// buffer; 2-buffer WAR skew argument unchanged). Only baseline-proven
// constructs: no inline asm, no placement assumptions.

typedef __bf16 bf16x8 __attribute__((ext_vector_type(8)));
typedef float f32x4 __attribute__((ext_vector_type(4)));

#define HS 768
#define GATES 3072
#define KV 1152          // combined K: 384 (W) + 768 (U)
#define SEQ 128
#define BATCH 128
#define OUT_HID (BATCH*SEQ*HS)
#define BPITCH 1160      // LDS row pitch (elems); rows 16B aligned
#define NWG 192
#define XH_BYTES ((size_t)2 * BATCH * 384 * 8)   // 2 ping-pong x 128 x 384 u64

__device__ __forceinline__ float fast_sig(float x) {
    return 1.0f / (1.0f + __expf(-x));
}
__device__ __forceinline__ float fast_tanh(float x) {
    x = fminf(fmaxf(x, -15.0f), 15.0f);
    float e = __expf(2.0f * x);
    return (e - 1.0f) / (e + 1.0f);
}

// convert 8 consecutive fp32 -> bf16x8 (RNE via cast)
__device__ __forceinline__ bf16x8 cvt8(const float* src) {
    float4 v0 = *(const float4*)src;
    float4 v1 = *(const float4*)(src + 4);
    bf16x8 p;
    p[0] = (__bf16)v0.x; p[1] = (__bf16)v0.y; p[2] = (__bf16)v0.z; p[3] = (__bf16)v0.w;
    p[4] = (__bf16)v1.x; p[5] = (__bf16)v1.y; p[6] = (__bf16)v1.z; p[7] = (__bf16)v1.w;
    return p;
}

// k-chunk swizzle: breaks the 8-way LDS bank conflict of row-strided reads
__device__ __forceinline__ int swz(int c8, int row) {
    return (c8 & ~3) | ((c8 & 3) ^ (row & 3));
}

// ---------------------------------------------------------------------------
// Kernel 1: masked + transposed weights (fp32 in, bf16 out).   [R4-validated]
// ---------------------------------------------------------------------------
__global__ void prep_kernel(const float* __restrict__ W, const float* __restrict__ U,
                            const float* __restrict__ G, __bf16* __restrict__ VmT) {
    __shared__ __bf16 tile[64][65];
    const int kvb = blockIdx.x * 64;
    const int cb  = blockIdx.y * 64;
    const int tid = threadIdx.x;
    {
        const int cl = tid & 63, kl0 = tid >> 6;
        #pragma unroll
        for (int i = 0; i < 16; ++i) {
            int kl = kl0 + i * 4;
            int kv = kvb + kl;
            int c  = cb + cl;
            int nout = (c % HS) >> 5;
            float g, v;
            if (kv < 384) {
                g = G[(kv >> 4) * 24 + nout];
                v = W[(size_t)kv * GATES + c];
            } else {
                int ku = kv - 384;
                g = G[(ku >> 5) * 24 + nout];
                v = U[(size_t)ku * GATES + c];
            }
            tile[kl][cl] = (__bf16)(v * g);
        }
    }
    __syncthreads();
    {
        const int kl = tid & 63, cl0 = tid >> 6;
        #pragma unroll
        for (int i = 0; i < 16; ++i) {
            int c = cl0 + i * 4;
            VmT[(size_t)(cb + c) * KV + kvb + kl] = tile[kl][c];
        }
    }
}

// ---------------------------------------------------------------------------
// Kernel 2: x fp32 [b][t][384] -> bf16 [t][b][384]
// ---------------------------------------------------------------------------
__global__ void prep_x(const float* __restrict__ x, __bf16* __restrict__ xb) {
    const int g = blockIdx.x * 256 + threadIdx.x;
    const int e = g * 8;
    const int b = e / (SEQ * 384);
    const int rem = e - b * (SEQ * 384);
    const int t = rem / 384;
    const int k = rem - t * 384;
    *(bf16x8*)&xb[((size_t)t * BATCH + b) * 384 + k] = cvt8(&x[e]);
}

// ---------------------------------------------------------------------------
// Kernel 3: persistent scan. 8 teams x 24 WGs = 192 WGs, 1 WG/CU.
// Per step: MFMA(72) -> LSTM -> u64 tagged exchange store -> out stores ->
// syncthreads -> issue 24 u64 h loads -> stage x_{t+1} (overlaps RTT) ->
// retry stale tags -> LDS-write h -> syncthreads.
// ---------------------------------------------------------------------------
__global__ __launch_bounds__(256, 1) void scan_kernel(
        const __bf16* __restrict__ xb,     // [t][b][384] bf16
        const float* __restrict__ h0,
        const float* __restrict__ c0,
        const __bf16* __restrict__ VmT,    // [3072][1152] bf16
        const float* __restrict__ bias,
        float* out,
        unsigned long long* xh64) {        // [2][128][384] {tag, bf16 pair}
    __shared__ __align__(16) __bf16 Bs[16 * BPITCH];
    const int tid = threadIdx.x;
    const int lane = tid & 63, wv = tid >> 6;
    const int m = lane & 15, quad = lane >> 4;
    const int team = blockIdx.x & 7, wg = blockIdx.x >> 3;
    const int bbase = team * 16;
    const int jbase = wg * 32 + wv * 8;

    // --- weights -> registers (read VmT exactly once for the whole scan) ---
    bf16x8 w[2][36];
    #pragma unroll
    for (int T = 0; T < 2; ++T) {
        const int cg = (m & 3) * HS + jbase + 2 * (m >> 2) + T;
        const __bf16* wp = VmT + (size_t)cg * KV;
        #pragma unroll
        for (int kk = 0; kk < 36; ++kk)
            w[T][kk] = *(const bf16x8*)(wp + kk * 32 + quad * 8);
    }

    const int b_own = bbase + m;
    const int j0 = jbase + 2 * quad;       // even
    const int j1 = j0 + 1;                 // odd (adjacent -> one u32)
    float cv0 = c0[b_own * HS + j0];
    float cv1 = c0[b_own * HS + j1];
    f32x4 bias0, bias1;
    #pragma unroll
    for (int r = 0; r < 4; ++r) {
        bias0[r] = bias[r * HS + j0];
        bias1[r] = bias[r * HS + j1];
    }

    const int bq = (quad ^ (m & 3));       // per-lane swizzled quad (B-frag)

    // --- pre-loop staging: x_0 (swizzled) + h0 (fp32 -> bf16, swizzled) ---
    #pragma unroll
    for (int i = 0; i < 3; ++i) {
        int ch = tid + i * 256;            // 768 x-chunks
        int row = ch / 48, c8 = ch % 48;
        *(uint4*)&Bs[row * BPITCH + swz(c8, row) * 8] =
            *(const uint4*)&xb[((size_t)0 * BATCH + bbase + row) * 384 + c8 * 8];
    }
    #pragma unroll
    for (int i = 0; i < 6; ++i) {
        int ch = tid + i * 256;            // 1536 h-chunks (bf16x8)
        int row = ch / 96, c8h = ch % 96;
        bf16x8 p = cvt8(&h0[(size_t)(bbase + row) * HS + c8h * 8]);
        *(bf16x8*)&Bs[row * BPITCH + (48 + swz(c8h, row)) * 8] = p;
    }
    __syncthreads();

    #pragma unroll 1
    for (int t = 0; t < SEQ; ++t) {
        // gates = bias + [x_t ; h_{t-1}] @ [Wm ; Um]
        f32x4 acc0 = bias0, acc1 = bias1;
        #pragma unroll
        for (int kk = 0; kk < 36; ++kk) {
            bf16x8 bf = *(const bf16x8*)&Bs[m * BPITCH + kk * 32 + bq * 8];
            acc0 = __builtin_amdgcn_mfma_f32_16x16x32_bf16(w[0][kk], bf, acc0, 0, 0, 0);
            acc1 = __builtin_amdgcn_mfma_f32_16x16x32_bf16(w[1][kk], bf, acc1, 0, 0, 0);
        }

        // LSTM elementwise (lane-local: acc reg index == gate i,f,g,o)
        float h0v, h1v;
        {
            float ii = fast_sig(acc0[0]), ff = fast_sig(acc0[1]);
            float gg = fast_tanh(acc0[2]), oo = fast_sig(acc0[3]);
            cv0 = ff * cv0 + ii * gg;
            h0v = oo * fast_tanh(cv0);
        }
        {
            float ii = fast_sig(acc1[0]), ff = fast_sig(acc1[1]);
            float gg = fast_tanh(acc1[2]), oo = fast_sig(acc1[3]);
            cv1 = ff * cv1 + ii * gg;
            h1v = oo * fast_tanh(cv1);
        }

        if (t == SEQ - 1) {
            const size_t obase = ((size_t)b_own * SEQ + t) * HS;
            out[obase + j0] = h0v;
            out[obase + j1] = h1v;
            out[OUT_HID + b_own * HS + j0] = h0v;
            out[OUT_HID + b_own * HS + j1] = h1v;
            out[OUT_HID + BATCH * HS + b_own * HS + j0] = cv0;
            out[OUT_HID + BATCH * HS + b_own * HS + j1] = cv1;
            break;
        }

        // tagged exchange store FIRST (earliest global visibility)
        {
            unsigned lo = (unsigned)__builtin_bit_cast(unsigned short, (__bf16)h0v);
            unsigned hi = (unsigned)__builtin_bit_cast(unsigned short, (__bf16)h1v);
            unsigned long long pk = ((unsigned long long)(unsigned)(t + 1) << 32)
                                  | (unsigned long long)(lo | (hi << 16));
            unsigned long long* dst = xh64 + ((size_t)(t & 1) * BATCH + b_own) * 384
                                           + (jbase >> 1) + quad;
            __hip_atomic_store(dst, pk, __ATOMIC_RELAXED, __HIP_MEMORY_SCOPE_AGENT);
        }
        {
            const size_t obase = ((size_t)b_own * SEQ + t) * HS;
            out[obase + j0] = h0v;
            out[obase + j1] = h1v;
        }

        __syncthreads();   // all waves done reading Bs (x + h regions)

        // issue all 24 tagged h loads for this team's 16 rows (in flight
        // while we stage x_{t+1} below)
        const unsigned long long* src64 = xh64 + (size_t)(t & 1) * BATCH * 384;
        unsigned long long v64[24];
        #pragma unroll
        for (int i = 0; i < 24; ++i) {
            int ch = tid + i * 256;            // 0..6143
            int row = ch / 384, u = ch % 384;
            v64[i] = __hip_atomic_load(&src64[(size_t)(bbase + row) * 384 + u],
                                       __ATOMIC_RELAXED, __HIP_MEMORY_SCOPE_AGENT);
        }

        // stage x_{t+1} (no cross-WG dependency; hides exchange RTT)
        #pragma unroll
        for (int i = 0; i < 3; ++i) {
            int ch = tid + i * 256;
            int row = ch / 48, c8 = ch % 48;
            *(uint4*)&Bs[row * BPITCH + swz(c8, row) * 8] =
                *(const uint4*)&xb[((size_t)(t + 1) * BATCH + bbase + row) * 384 + c8 * 8];
        }

        // retry stale entries until every tag reads t+1 (producers store
        // unconditionally before they can block -> always terminates)
        {
            const unsigned tag = (unsigned)(t + 1);
            for (;;) {
                bool any = false;
                #pragma unroll
                for (int i = 0; i < 24; ++i)
                    if ((unsigned)(v64[i] >> 32) != tag) any = true;
                if (!any) break;
                #pragma unroll
                for (int i = 0; i < 24; ++i) {
                    if ((unsigned)(v64[i] >> 32) != tag) {
                        int ch = tid + i * 256;
                        int row = ch / 384, u = ch % 384;
                        v64[i] = __hip_atomic_load(
                            &src64[(size_t)(bbase + row) * 384 + u],
                            __ATOMIC_RELAXED, __HIP_MEMORY_SCOPE_AGENT);
                    }
                }
            }
        }

        // LDS-write h (same swizzled layout as before)
        #pragma unroll
        for (int i = 0; i < 24; ++i) {
            int ch = tid + i * 256;
            int row = ch / 384, u = ch % 384;
            int c8h = u >> 2;                  // h-region chunk (8 elems)
            int eo = (u & 3) * 2;              // elem offset within chunk
            *(unsigned*)&Bs[row * BPITCH + (48 + swz(c8h, row)) * 8 + eo] =
                (unsigned)v64[i];
        }
        __syncthreads();
    }
}

// ---------------------------------------------------------------------------
extern "C" void kernel_launch(void* const* d_in, const int* in_sizes, int n_in,
                              void* d_out, int out_size, void* d_ws, size_t ws_size,
                              hipStream_t stream) {
    (void)in_sizes; (void)n_in; (void)out_size; (void)ws_size;
    const float* x    = (const float*)d_in[0];
    const float* h0   = (const float*)d_in[1];
    const float* c0   = (const float*)d_in[2];
    const float* W    = (const float*)d_in[3];
    const float* U    = (const float*)d_in[4];
    const float* bias = (const float*)d_in[5];
    const float* G    = (const float*)d_in[6];
    float* out = (float*)d_out;

    char* wsb = (char*)d_ws;
    unsigned long long* xh64 = (unsigned long long*)wsb;            // 768 KB
    __bf16* VmT = (__bf16*)(wsb + XH_BYTES);                        // 6.75 MB
    __bf16* xb  = (__bf16*)(wsb + XH_BYTES + (size_t)GATES * KV * 2); // 12.6 MB

    hipMemsetAsync(xh64, 0, XH_BYTES, stream);   // tags start at 0; first tag is 1
    prep_kernel<<<dim3(18, 48), 256, 0, stream>>>(W, U, G, VmT);
    prep_x<<<dim3(3072), 256, 0, stream>>>(x, xb);
    scan_kernel<<<dim3(NWG), dim3(256), 0, stream>>>(xb, h0, c0, VmT, bias,
                                                     out, xh64);
}

// Round 4
// 591.221 us; speedup vs baseline: 2.0058x; 2.0058x over previous
//
#include <hip/hip_runtime.h>
#include <hip/hip_bf16.h>

// GraphLSTM: B=128, S=128, N=24, F=16, H=32 -> IS=384, HS=768, gates=3072.
// R11: baseline (640us) skeleton with the team barrier rebuilt as per-WG
// FLAG LINES. The baseline's cost chain was: atomicExch + vmcnt drain ->
// 24 serialized RMWs on ONE counter line -> s_sleep-quantized poll by one
// lane -> bulk data load. R10 proved polling bulk DATA is disastrous
// (6144-load retry rounds doubled FETCH_SIZE). Here only the control
// surface changes: tid0 stores flag[wg]=t+1 after the vmcnt-draining
// __syncthreads(); consumers poll the 24 flag lines IN PARALLEL (wave 0,
// lanes 0..23, one line each, no sleep). Data moves exactly once via the
// baseline's bulk 24-u32 loads. Exchange stores are relaxed atomic stores
// (R10-proven coherent; no RMW). 2-buffer WAR skew argument unchanged:
// flag t+2 can only be stored after the WG finished step-t's data read.

typedef __bf16 bf16x8 __attribute__((ext_vector_type(8)));
typedef float f32x4 __attribute__((ext_vector_type(4)));

#define HS 768
#define GATES 3072
#define KV 1152          // combined K: 384 (W) + 768 (U)
#define SEQ 128
#define BATCH 128
#define OUT_HID (BATCH*SEQ*HS)
#define BPITCH 1160      // LDS row pitch (elems); rows 16B aligned
#define NWG 192
#define TEAM_WGS 24

__device__ __forceinline__ float fast_sig(float x) {
    return 1.0f / (1.0f + __expf(-x));
}
__device__ __forceinline__ float fast_tanh(float x) {
    x = fminf(fmaxf(x, -15.0f), 15.0f);
    float e = __expf(2.0f * x);
    return (e - 1.0f) / (e + 1.0f);
}

// convert 8 consecutive fp32 -> bf16x8 (RNE via cast)
__device__ __forceinline__ bf16x8 cvt8(const float* src) {
    float4 v0 = *(const float4*)src;
    float4 v1 = *(const float4*)(src + 4);
    bf16x8 p;
    p[0] = (__bf16)v0.x; p[1] = (__bf16)v0.y; p[2] = (__bf16)v0.z; p[3] = (__bf16)v0.w;
    p[4] = (__bf16)v1.x; p[5] = (__bf16)v1.y; p[6] = (__bf16)v1.z; p[7] = (__bf16)v1.w;
    return p;
}

// k-chunk swizzle: breaks the 8-way LDS bank conflict of row-strided reads
__device__ __forceinline__ int swz(int c8, int row) {
    return (c8 & ~3) | ((c8 & 3) ^ (row & 3));
}

// ---------------------------------------------------------------------------
// Kernel 1: masked + transposed weights (fp32 in, bf16 out).   [R4-validated]
// ---------------------------------------------------------------------------
__global__ void prep_kernel(const float* __restrict__ W, const float* __restrict__ U,
                            const float* __restrict__ G, __bf16* __restrict__ VmT) {
    __shared__ __bf16 tile[64][65];
    const int kvb = blockIdx.x * 64;
    const int cb  = blockIdx.y * 64;
    const int tid = threadIdx.x;
    {
        const int cl = tid & 63, kl0 = tid >> 6;
        #pragma unroll
        for (int i = 0; i < 16; ++i) {
            int kl = kl0 + i * 4;
            int kv = kvb + kl;
            int c  = cb + cl;
            int nout = (c % HS) >> 5;
            float g, v;
            if (kv < 384) {
                g = G[(kv >> 4) * 24 + nout];
                v = W[(size_t)kv * GATES + c];
            } else {
                int ku = kv - 384;
                g = G[(ku >> 5) * 24 + nout];
                v = U[(size_t)ku * GATES + c];
            }
            tile[kl][cl] = (__bf16)(v * g);
        }
    }
    __syncthreads();
    {
        const int kl = tid & 63, cl0 = tid >> 6;
        #pragma unroll
        for (int i = 0; i < 16; ++i) {
            int c = cl0 + i * 4;
            VmT[(size_t)(cb + c) * KV + kvb + kl] = tile[kl][c];
        }
    }
}

// ---------------------------------------------------------------------------
// Kernel 2: x fp32 [b][t][384] -> bf16 [t][b][384]
// ---------------------------------------------------------------------------
__global__ void prep_x(const float* __restrict__ x, __bf16* __restrict__ xb) {
    const int g = blockIdx.x * 256 + threadIdx.x;
    const int e = g * 8;
    const int b = e / (SEQ * 384);
    const int rem = e - b * (SEQ * 384);
    const int t = rem / 384;
    const int k = rem - t * 384;
    *(bf16x8*)&xb[((size_t)t * BATCH + b) * 384 + k] = cvt8(&x[e]);
}

// ---------------------------------------------------------------------------
// Kernel 3: persistent scan. 8 teams x 24 WGs = 192 WGs, 1 WG/CU.
// bar layout (16 KB, zeroed per launch):
//   flags: u32[8][24][16] -- one 64B line per (team,wg), value = t+1
// Per step: MFMA(72) -> LSTM -> exchange store (relaxed) + out stores ->
// syncthreads (drains vmcnt: data at coherence point) -> tid0 flag store ->
// stage x_{t+1} (overlaps flag RTT) -> wave0 lanes<24 poll 24 flag lines in
// parallel -> syncthreads -> bulk 24-u32 h loads -> LDS write -> syncthreads.
// ---------------------------------------------------------------------------
__global__ __launch_bounds__(256, 1) void scan_kernel(
        const __bf16* __restrict__ xb,     // [t][b][384] bf16
        const float* __restrict__ h0,
        const float* __restrict__ c0,
        const __bf16* __restrict__ VmT,    // [3072][1152] bf16
        const float* __restrict__ bias,
        float* out,
        unsigned* xh32,                    // [2][128][384] packed bf16 pairs
        unsigned* bar) {
    __shared__ __align__(16) __bf16 Bs[16 * BPITCH];
    const int tid = threadIdx.x;
    const int lane = tid & 63, wv = tid >> 6;
    const int m = lane & 15, quad = lane >> 4;
    const int team = blockIdx.x & 7, wg = blockIdx.x >> 3;
    const int bbase = team * 16;
    const int jbase = wg * 32 + wv * 8;

    unsigned* flags = bar;                              // [8][24][16]
    unsigned* myflag = flags + (team * TEAM_WGS + wg) * 16;

    // --- weights -> registers (read VmT exactly once for the whole scan) ---
    bf16x8 w[2][36];
    #pragma unroll
    for (int T = 0; T < 2; ++T) {
        const int cg = (m & 3) * HS + jbase + 2 * (m >> 2) + T;
        const __bf16* wp = VmT + (size_t)cg * KV;
        #pragma unroll
        for (int kk = 0; kk < 36; ++kk)
            w[T][kk] = *(const bf16x8*)(wp + kk * 32 + quad * 8);
    }

    const int b_own = bbase + m;
    const int j0 = jbase + 2 * quad;       // even
    const int j1 = j0 + 1;                 // odd (adjacent -> one u32)
    float cv0 = c0[b_own * HS + j0];
    float cv1 = c0[b_own * HS + j1];
    f32x4 bias0, bias1;
    #pragma unroll
    for (int r = 0; r < 4; ++r) {
        bias0[r] = bias[r * HS + j0];
        bias1[r] = bias[r * HS + j1];
    }

    const int bq = (quad ^ (m & 3));       // per-lane swizzled quad (B-frag)

    // --- pre-loop staging: x_0 (swizzled) + h0 (fp32 -> bf16, swizzled) ---
    #pragma unroll
    for (int i = 0; i < 3; ++i) {
        int ch = tid + i * 256;            // 768 x-chunks
        int row = ch / 48, c8 = ch % 48;
        *(uint4*)&Bs[row * BPITCH + swz(c8, row) * 8] =
            *(const uint4*)&xb[((size_t)0 * BATCH + bbase + row) * 384 + c8 * 8];
    }
    #pragma unroll
    for (int i = 0; i < 6; ++i) {
        int ch = tid + i * 256;            // 1536 h-chunks (bf16x8)
        int row = ch / 96, c8h = ch % 96;
        bf16x8 p = cvt8(&h0[(size_t)(bbase + row) * HS + c8h * 8]);
        *(bf16x8*)&Bs[row * BPITCH + (48 + swz(c8h, row)) * 8] = p;
    }
    __syncthreads();

    #pragma unroll 1
    for (int t = 0; t < SEQ; ++t) {
        // gates = bias + [x_t ; h_{t-1}] @ [Wm ; Um]
        f32x4 acc0 = bias0, acc1 = bias1;
        #pragma unroll
        for (int kk = 0; kk < 36; ++kk) {
            bf16x8 bf = *(const bf16x8*)&Bs[m * BPITCH + kk * 32 + bq * 8];
            acc0 = __builtin_amdgcn_mfma_f32_16x16x32_bf16(w[0][kk], bf, acc0, 0, 0, 0);
            acc1 = __builtin_amdgcn_mfma_f32_16x16x32_bf16(w[1][kk], bf, acc1, 0, 0, 0);
        }

        // LSTM elementwise (lane-local: acc reg index == gate i,f,g,o)
        float h0v, h1v;
        {
            float ii = fast_sig(acc0[0]), ff = fast_sig(acc0[1]);
            float gg = fast_tanh(acc0[2]), oo = fast_sig(acc0[3]);
            cv0 = ff * cv0 + ii * gg;
            h0v = oo * fast_tanh(cv0);
        }
        {
            float ii = fast_sig(acc1[0]), ff = fast_sig(acc1[1]);
            float gg = fast_tanh(acc1[2]), oo = fast_sig(acc1[3]);
            cv1 = ff * cv1 + ii * gg;
            h1v = oo * fast_tanh(cv1);
        }

        if (t == SEQ - 1) {
            const size_t obase = ((size_t)b_own * SEQ + t) * HS;
            out[obase + j0] = h0v;
            out[obase + j1] = h1v;
            out[OUT_HID + b_own * HS + j0] = h0v;
            out[OUT_HID + b_own * HS + j1] = h1v;
            out[OUT_HID + BATCH * HS + b_own * HS + j0] = cv0;
            out[OUT_HID + BATCH * HS + b_own * HS + j1] = cv1;
            break;
        }

        // exchange store FIRST (earliest global visibility; relaxed, no RMW)
        {
            unsigned lo = (unsigned)__builtin_bit_cast(unsigned short, (__bf16)h0v);
            unsigned hi = (unsigned)__builtin_bit_cast(unsigned short, (__bf16)h1v);
            unsigned* dst = xh32 + ((size_t)(t & 1) * BATCH + b_own) * 384
                                 + (jbase >> 1) + quad;
            __hip_atomic_store(dst, lo | (hi << 16), __ATOMIC_RELAXED,
                               __HIP_MEMORY_SCOPE_AGENT);
        }
        {
            const size_t obase = ((size_t)b_own * SEQ + t) * HS;
            out[obase + j0] = h0v;
            out[obase + j1] = h1v;
        }

        __syncthreads();   // LDS free + ALL waves' exchange stores vmcnt-drained

        // publish: one relaxed flag store per WG (own 64B line, no RMW)
        if (tid == 0)
            __hip_atomic_store(myflag, (unsigned)(t + 1), __ATOMIC_RELAXED,
                               __HIP_MEMORY_SCOPE_AGENT);

        // stage x_{t+1} (no cross-WG dependency; overlaps flag propagation)
        #pragma unroll
        for (int i = 0; i < 3; ++i) {
            int ch = tid + i * 256;
            int row = ch / 48, c8 = ch % 48;
            *(uint4*)&Bs[row * BPITCH + swz(c8, row) * 8] =
                *(const uint4*)&xb[((size_t)(t + 1) * BATCH + bbase + row) * 384 + c8 * 8];
        }

        // team barrier: 24 flag lines polled in parallel by wave 0
        if (wv == 0 && lane < TEAM_WGS) {
            const unsigned* fp = flags + (team * TEAM_WGS + lane) * 16;
            while (__hip_atomic_load(fp, __ATOMIC_RELAXED,
                                     __HIP_MEMORY_SCOPE_AGENT) < (unsigned)(t + 1)) {
            }
        }
        __syncthreads();

        // stage h_t: FULL 16 rows x 384 u32 = 6144 (24 per thread), ONCE
        {
            const unsigned* src = xh32 + (size_t)(t & 1) * BATCH * 384;
            unsigned vals[24];
            #pragma unroll
            for (int i = 0; i < 24; ++i) {
                int ch = tid + i * 256;            // 0..6143
                int row = ch / 384, u = ch % 384;
                vals[i] = __hip_atomic_load(&src[(size_t)(bbase + row) * 384 + u],
                                            __ATOMIC_RELAXED, __HIP_MEMORY_SCOPE_AGENT);
            }
            #pragma unroll
            for (int i = 0; i < 24; ++i) {
                int ch = tid + i * 256;
                int row = ch / 384, u = ch % 384;
                int c8h = u >> 2;                  // h-region chunk (8 elems)
                int eo = (u & 3) * 2;              // elem offset within chunk
                *(unsigned*)&Bs[row * BPITCH + (48 + swz(c8h, row)) * 8 + eo] = vals[i];
            }
        }
        __syncthreads();
    }
}

// ---------------------------------------------------------------------------
extern "C" void kernel_launch(void* const* d_in, const int* in_sizes, int n_in,
                              void* d_out, int out_size, void* d_ws, size_t ws_size,
                              hipStream_t stream) {
    (void)in_sizes; (void)n_in; (void)out_size; (void)ws_size;
    const float* x    = (const float*)d_in[0];
    const float* h0   = (const float*)d_in[1];
    const float* c0   = (const float*)d_in[2];
    const float* W    = (const float*)d_in[3];
    const float* U    = (const float*)d_in[4];
    const float* bias = (const float*)d_in[5];
    const float* G    = (const float*)d_in[6];
    float* out = (float*)d_out;

    char* wsb = (char*)d_ws;
    unsigned* bar = (unsigned*)wsb;                                    // 16 KB
    __bf16* VmT  = (__bf16*)(wsb + 16384);                             // 6.75 MB
    __bf16* xb   = (__bf16*)(wsb + 16384 + (size_t)GATES * KV * 2);    // 12.6 MB
    unsigned* xh32 = (unsigned*)(wsb + 16384 + (size_t)GATES * KV * 2
                                      + (size_t)SEQ * BATCH * 384 * 2);   // 393 KB

    hipMemsetAsync(bar, 0, 16384, stream);
    prep_kernel<<<dim3(18, 48), 256, 0, stream>>>(W, U, G, VmT);
    prep_x<<<dim3(3072), 256, 0, stream>>>(x, xb);
    scan_kernel<<<dim3(NWG), dim3(256), 0, stream>>>(xb, h0, c0, VmT, bias,
                                                     out, xh32, bar);
}